// Round 2
// baseline (1841.744 us; speedup 1.0000x reference)
//
#include <hip/hip_runtime.h>
#include <cmath>

#define S       65
#define SP      68              // padded row stride (floats), 272 B (16B-aligned rows)
#define REC     (S*SP)          // 4420 floats per matrix record (16B-multiple)
#define F4      (REC/4)         // 1105 float4s
#define VOCAB   1024
#define EMS     68              // em_pT row stride
#define NTH     256
#define RT      5               // rows per thread tile
#define CT      4               // cols per thread tile (float4)
#define PSEG    768             // segment blocks (3 per CU)
#define GROUP   12
#define NGROUPS (PSEG/GROUP)    // 64

__device__ __forceinline__ float wave_max(float v) {
  #pragma unroll
  for (int o = 32; o > 0; o >>= 1) v = fmaxf(v, __shfl_xor(v, o));
  return v;
}
__device__ __forceinline__ float wave_sumf(float v) {
  #pragma unroll
  for (int o = 32; o > 0; o >>= 1) v += __shfl_xor(v, o);
  return v;
}
__device__ __forceinline__ int wave_sumi(int v) {
  #pragma unroll
  for (int o = 32; o > 0; o >>= 1) v += __shfl_xor(v, o);
  return v;
}

// 65x65(x68-col) fp32 matmul tile: thread computes RT x CT outputs.
// All LDS reads are aligned float4 at thread-base + compile-time offset.
__device__ __forceinline__ void mm_tile(const float* Rl, const float* Cl,
                                        int r0, int c0, float acc[RT][CT]) {
  const float* rp = Rl + r0 * SP;
  const float* cp = Cl + c0;
  #pragma unroll
  for (int jb = 0; jb < 16; ++jb) {
    float4 cv4[4];
    float4 rv4[RT];
    #pragma unroll
    for (int k = 0; k < 4; ++k) cv4[k] = *(const float4*)(cp + (4*jb + k) * SP);
    #pragma unroll
    for (int q = 0; q < RT; ++q) rv4[q] = *(const float4*)(rp + q * SP + 4*jb);
    #pragma unroll
    for (int q = 0; q < RT; ++q) {
      const float rr[4] = {rv4[q].x, rv4[q].y, rv4[q].z, rv4[q].w};
      #pragma unroll
      for (int k = 0; k < 4; ++k) {
        const float cc[4] = {cv4[k].x, cv4[k].y, cv4[k].z, cv4[k].w};
        #pragma unroll
        for (int u = 0; u < CT; ++u)
          acc[q][u] = fmaf(rr[k], cc[u], acc[q][u]);
      }
    }
  }
  { // tail j = 64
    const float4 c4 = *(const float4*)(cp + 64 * SP);
    const float cc[4] = {c4.x, c4.y, c4.z, c4.w};
    #pragma unroll
    for (int q = 0; q < RT; ++q) {
      float rr = rp[q * SP + 64];
      #pragma unroll
      for (int u = 0; u < CT; ++u) acc[q][u] = fmaf(rr, cc[u], acc[q][u]);
    }
  }
}

// ---------- K1a: row softmax of log_trans -> transition probs a_prob[65][SP]
__global__ void k_trans_prep(const float* __restrict__ lt, float* __restrict__ a_prob) {
  int i = blockIdx.x, t = threadIdx.x;           // 64 threads, one wave
  float x0 = lt[i*S + t];
  float x1 = (t == 0) ? lt[i*S + 64] : -1e30f;
  float m = wave_max(fmaxf(x0, x1));
  float e0 = expf(x0 - m);
  float e1 = (t == 0) ? expf(x1 - m) : 0.f;
  float ssum = wave_sumf(e0 + e1);
  float inv = 1.f / ssum;
  a_prob[i*SP + t] = e0 * inv;
  if (t == 0) a_prob[i*SP + 64] = e1 * inv;
  if (t < 3)  a_prob[i*SP + 65 + t] = 0.f;       // zero pad cols
}

// ---------- K1b: row softmax of log_em -> em_pT[v][j] (transposed), stride EMS
__global__ __launch_bounds__(NTH) void k_em_prep(const float* __restrict__ le,
                                                 float* __restrict__ em_pT) {
  int j = blockIdx.x, t = threadIdx.x;
  const float* row = le + (size_t)j * VOCAB;
  float x[4];
  float m = -1e30f;
  #pragma unroll
  for (int q = 0; q < 4; ++q) { x[q] = row[t + 256*q]; m = fmaxf(m, x[q]); }
  m = wave_max(m);
  __shared__ float wred[4], wsum[4];
  int w = t >> 6, lane = t & 63;
  if (lane == 0) wred[w] = m;
  __syncthreads();
  m = fmaxf(fmaxf(wred[0], wred[1]), fmaxf(wred[2], wred[3]));
  float s = 0.f;
  #pragma unroll
  for (int q = 0; q < 4; ++q) s += expf(x[q] - m);
  s = wave_sumf(s);
  if (lane == 0) wsum[w] = s;
  __syncthreads();
  float inv = 1.f / (wsum[0] + wsum[1] + wsum[2] + wsum[3]);
  #pragma unroll
  for (int q = 0; q < 4; ++q)
    em_pT[(size_t)(t + 256*q) * EMS + j] = expf(x[q] - m) * inv;
}

// ---------- K2: pair table C_v = A * diag(e_v) * A   (1024 blocks)
__global__ __launch_bounds__(NTH) void k_pair(const float* __restrict__ a_prob,
                                              const float* __restrict__ em_pT,
                                              float* __restrict__ Ctab) {
  __shared__ __align__(16) float aL[REC];
  __shared__ __align__(16) float bL[REC];
  int v = blockIdx.x, t = threadIdx.x;
  {
    const float4* src = (const float4*)a_prob;
    float4* dst = (float4*)aL;
    for (int u = t; u < F4; u += NTH) dst[u] = src[u];
  }
  __syncthreads();
  for (int u = t; u < REC; u += NTH) {
    int j = u / SP;
    bL[u] = em_pT[(size_t)v * EMS + j] * aL[u];
  }
  __syncthreads();
  int rt = t / 17, ct = t % 17;
  bool act = rt < 13;
  int r0 = act ? rt * RT : 0;
  int c0 = ct * CT;
  float acc[RT][CT] = {};
  mm_tile(aL, bL, r0, c0, acc);
  float* dst = Ctab + (size_t)v * REC;
  if (act) {
    #pragma unroll
    for (int q = 0; q < RT; ++q) {
      float4 o; o.x = acc[q][0]; o.y = acc[q][1]; o.z = acc[q][2]; o.w = acc[q][3];
      *(float4*)(dst + (r0+q)*SP + c0) = o;   // pad cols come out exactly 0
    }
  }
}

// ---------- K3: segment chain product with deferred power-of-2 rescaling
__global__ __launch_bounds__(NTH, 3) void k_seg(const float* __restrict__ Ctab,
    const float* __restrict__ em_pT, const int* __restrict__ obvs,
    float* __restrict__ Rseg, int* __restrict__ eacc_out, int NP) {
  __shared__ __align__(16) float Rb[2][REC];
  __shared__ __align__(16) float Cb[REC];
  __shared__ float evb[2][SP];
  __shared__ int smax[2];

  const int p = blockIdx.x, t = threadIdx.x;
  const int base = NP / PSEG, rem = NP % PSEG;
  const int k0 = p*base + (p < rem ? p : rem);
  const int L  = base + (p < rem ? 1 : 0);
  const int rt = t / 17, ct = t % 17;
  const bool act = rt < 13;
  const int r0 = act ? rt * RT : 0;            // clamped: all reads in-bounds
  const int c0 = ct * CT;

  for (int u = t; u < REC; u += NTH) {
    int j = u / SP, k = u - j*SP;
    Rb[0][u] = (j == k) ? 1.f : 0.f;           // identity, zero pads
  }
  if (t == 0) { smax[0] = 0; smax[1] = 0; }
  if (L > 0) {
    int o1 = obvs[1 + 2*k0], o2 = obvs[2 + 2*k0];
    const float4* src = (const float4*)(Ctab + (size_t)o1 * REC);
    float4* dst = (float4*)Cb;
    for (int u = t; u < F4; u += NTH) dst[u] = src[u];
    float ev0 = (t < S) ? em_pT[(size_t)o2 * EMS + t] : 0.f;
    if (t < SP) evb[0][t] = ev0;
  }
  __syncthreads();

  int cur = 0;
  int my_eacc = 0;
  float scale = 1.f;
  for (int s = 0; s < L; ++s) {
    // deferred scale: previous step's block max, folded into this step's ev mult
    if (s > 0) {
      int bm = smax[(s-1) & 1];
      int e = (bm >> 23) - 127;
      my_eacc += e;
      scale = __int_as_float((127 - e) << 23);  // exact 2^-e
    }
    // stage next C + ev into registers (issue early, write after barrier A)
    int kn = k0 + s + 1; if (kn > NP - 1) kn = NP - 1;
    int o1n = obvs[1 + 2*kn], o2n = obvs[2 + 2*kn];
    const float4* src4 = (const float4*)(Ctab + (size_t)o1n * REC);
    float4 creg[5];
    #pragma unroll
    for (int q = 0; q < 5; ++q) {
      int u = t + q*NTH;
      creg[q] = (u < F4) ? src4[u] : make_float4(0.f, 0.f, 0.f, 0.f);
    }
    float evreg = (t < S) ? em_pT[(size_t)o2n * EMS + t] : 0.f;

    // matmul acc = R * C
    float acc[RT][CT] = {};
    mm_tile(Rb[cur], Cb, r0, c0, acc);

    // block max of acc (pre-emission) for next step's rescale
    float mx = 0.f;
    if (act) {
      #pragma unroll
      for (int q = 0; q < RT; ++q)
        #pragma unroll
        for (int u = 0; u < CT; ++u) mx = fmaxf(mx, acc[q][u]);
    }
    mx = wave_max(mx);
    if ((t & 63) == 0) atomicMax(&smax[s & 1], __float_as_int(mx));
    __syncthreads();                          // barrier A: Cb reads + smax reads done

    { // write staged C/ev
      float4* dst4 = (float4*)Cb;
      #pragma unroll
      for (int q = 0; q < 5; ++q) {
        int u = t + q*NTH;
        if (u < F4) dst4[u] = creg[q];
      }
      if (t < SP) evb[(s+1) & 1][t] = evreg;
    }
    if (t == 0) smax[(s+1) & 1] = 0;          // reset slot for step s+1
    if (act) {
      float4 ev4 = *(const float4*)(&evb[s & 1][c0]);
      const float evs[4] = {ev4.x*scale, ev4.y*scale, ev4.z*scale, ev4.w*scale};
      float* rdst = Rb[cur ^ 1] + r0*SP + c0;
      #pragma unroll
      for (int q = 0; q < RT; ++q) {
        float4 o;
        o.x = acc[q][0]*evs[0]; o.y = acc[q][1]*evs[1];
        o.z = acc[q][2]*evs[2]; o.w = acc[q][3]*evs[3];
        *(float4*)(rdst + q*SP) = o;
      }
    }
    __syncthreads();                          // barrier B
    cur ^= 1;
  }

  { // write out; last step's max never applied (and never counted) — exact bookkeeping
    const float4* src = (const float4*)(Rb[cur]);
    float4* dst = (float4*)(Rseg + (size_t)p * REC);
    for (int u = t; u < F4; u += NTH) dst[u] = src[u];
  }
  if (t == 0) eacc_out[p] = my_eacc;
}

// ---------- K4: chain 12 consecutive segment matrices per block
__global__ __launch_bounds__(NTH) void k_chain(const float* __restrict__ Rseg,
    float* __restrict__ Rm, int* __restrict__ eacc2) {
  __shared__ __align__(16) float Rb[2][REC];
  __shared__ __align__(16) float Cb[REC];
  __shared__ int smax[2];
  const int g = blockIdx.x, t = threadIdx.x;
  const int rt = t / 17, ct = t % 17;
  const bool act = rt < 13;
  const int r0 = act ? rt * RT : 0;
  const int c0 = ct * CT;
  {
    const float4* src = (const float4*)(Rseg + (size_t)(g*GROUP) * REC);
    float4* dst = (float4*)(Rb[0]);
    for (int u = t; u < F4; u += NTH) dst[u] = src[u];
  }
  if (t == 0) { smax[0] = 0; smax[1] = 0; }
  __syncthreads();
  int cur = 0, my_e = 0;
  for (int q2 = 1; q2 < GROUP; ++q2) {
    const float4* src = (const float4*)(Rseg + (size_t)(g*GROUP + q2) * REC);
    float4* dstc = (float4*)Cb;
    for (int u = t; u < F4; u += NTH) dstc[u] = src[u];
    __syncthreads();                          // B1
    float acc[RT][CT] = {};
    mm_tile(Rb[cur], Cb, r0, c0, acc);
    float mx = 0.f;
    if (act) {
      #pragma unroll
      for (int q = 0; q < RT; ++q)
        #pragma unroll
        for (int u = 0; u < CT; ++u) mx = fmaxf(mx, acc[q][u]);
    }
    mx = wave_max(mx);
    if ((t & 63) == 0) atomicMax(&smax[q2 & 1], __float_as_int(mx));
    __syncthreads();                          // B2
    int bm = smax[q2 & 1];
    int e = (bm >> 23) - 127;
    float scale = __int_as_float((127 - e) << 23);
    my_e += e;
    if (t == 0) smax[(q2+1) & 1] = 0;
    if (act) {
      float* rdst = Rb[cur ^ 1] + r0*SP + c0;
      #pragma unroll
      for (int q = 0; q < RT; ++q) {
        float4 o;
        o.x = acc[q][0]*scale; o.y = acc[q][1]*scale;
        o.z = acc[q][2]*scale; o.w = acc[q][3]*scale;
        *(float4*)(rdst + q*SP) = o;
      }
    }
    __syncthreads();
    cur ^= 1;
  }
  {
    const float4* src = (const float4*)(Rb[cur]);
    float4* dst = (float4*)(Rm + (size_t)g * REC);
    for (int u = t; u < F4; u += NTH) dst[u] = src[u];
  }
  if (t == 0) eacc2[g] = my_e;
}

// ---------- K5: final vector sweep + termination + log (single block)
__global__ __launch_bounds__(NTH) void k_final(const float* __restrict__ Rm,
    const float* __restrict__ lt, const int* __restrict__ e1, const int* __restrict__ e2,
    const float* __restrict__ a_prob, const float* __restrict__ em_pT,
    const int* __restrict__ obvs, float* __restrict__ out, int N) {
  __shared__ __align__(16) float Mb[2][REC];
  __shared__ float vL[SP];
  __shared__ float prod[SP];
  __shared__ int smax[2];
  __shared__ int esum_s;
  const int t = threadIdx.x, lane = t & 63;
  if (t == 0) { esum_s = 0; smax[0] = 0; smax[1] = 0; }
  if (t < S) vL[t] = (t == 0) ? 1.f : expf(-20.0f);   // exp(log_pi)
  {
    const float4* src = (const float4*)Rm;
    float4* dst = (float4*)(Mb[0]);
    for (int u = t; u < F4; u += NTH) dst[u] = src[u];
  }
  __syncthreads();
  {
    int es = 0;
    for (int u = t; u < PSEG; u += NTH) es += e1[u];
    for (int u = t; u < NGROUPS; u += NTH) es += e2[u];
    es = wave_sumi(es);
    if (lane == 0) atomicAdd(&esum_s, es);
  }
  int cur = 0, my_e = 0;
  for (int m = 0; m < NGROUPS; ++m) {
    if (m + 1 < NGROUPS) {
      const float4* src = (const float4*)(Rm + (size_t)(m+1) * REC);
      float4* dst = (float4*)(Mb[cur ^ 1]);
      for (int u = t; u < F4; u += NTH) dst[u] = src[u];
    }
    float acc = 0.f;
    if (t < S) {
      const float* Mp = Mb[cur];
      #pragma unroll 5
      for (int i = 0; i < S; ++i) acc = fmaf(vL[i], Mp[i*SP + t], acc);
    }
    float mx = (t < S) ? acc : 0.f;
    mx = wave_max(mx);
    if (lane == 0) atomicMax(&smax[m & 1], __float_as_int(mx));
    __syncthreads();                          // (1)
    int bm = smax[m & 1];
    int e = (bm >> 23) - 127;
    float scale = __int_as_float((127 - e) << 23);
    my_e += e;
    if (t == 0) smax[(m+1) & 1] = 0;
    if (t < S) vL[t] = acc * scale;
    __syncthreads();                          // (2)
    cur ^= 1;
  }
  if (N & 1) {                                // leftover unpaired step
    int oN = obvs[N];
    float acc2 = 0.f;
    if (t < S) {
      #pragma unroll 5
      for (int i = 0; i < S; ++i) acc2 = fmaf(vL[i], a_prob[i*SP + t], acc2);
      acc2 *= em_pT[(size_t)oN * EMS + t];
    }
    __syncthreads();
    if (t < S) vL[t] = acc2;
    __syncthreads();
  }
  if (t < S) prod[t] = vL[t] * expf(lt[t*S]);  // raw log_trans[:,0]
  __syncthreads();
  if (t == 0) {
    double z = 0.0;
    for (int i = 0; i < S; ++i) z += (double)prod[i];
    double logz = log(z) + (double)(esum_s + my_e) * 0.69314718055994530942;
    out[0] = (float)logz;
  }
}

extern "C" void kernel_launch(void* const* d_in, const int* in_sizes, int n_in,
                              void* d_out, int out_size, void* d_ws, size_t ws_size,
                              hipStream_t stream) {
  (void)n_in; (void)out_size;
  const int*   obvs = (const int*)d_in[0];
  const float* lt   = (const float*)d_in[1];
  const float* le   = (const float*)d_in[2];
  float* out = (float*)d_out;
  const int T  = in_sizes[0];
  const int N  = T - 2;          // scan length
  const int NP = N >> 1;         // pair count

  float* ws = (float*)d_ws;
  size_t off = 0;
  float* a_prob = ws + off; off += REC;                     // 4420
  float* em_pT  = ws + off; off += (size_t)VOCAB * EMS;     // 69632
  float* Ctab   = ws + off; off += (size_t)VOCAB * REC;     // 4,526,080
  float* Rseg   = ws + off; off += (size_t)PSEG * REC;      // 3,394,560
  float* Rm     = ws + off; off += (size_t)NGROUPS * REC;   // 282,880
  int* e1 = (int*)(ws + off); off += PSEG;
  int* e2 = (int*)(ws + off); off += NGROUPS;
  if (ws_size < off * sizeof(float)) return;                // ~33.1 MiB needed

  k_trans_prep<<<dim3(S), dim3(64), 0, stream>>>(lt, a_prob);
  k_em_prep  <<<dim3(S), dim3(NTH), 0, stream>>>(le, em_pT);
  k_pair     <<<dim3(VOCAB), dim3(NTH), 0, stream>>>(a_prob, em_pT, Ctab);
  k_seg      <<<dim3(PSEG), dim3(NTH), 0, stream>>>(Ctab, em_pT, obvs, Rseg, e1, NP);
  k_chain    <<<dim3(NGROUPS), dim3(NTH), 0, stream>>>(Rseg, Rm, e2);
  k_final    <<<dim3(1), dim3(NTH), 0, stream>>>(Rm, lt, e1, e2, a_prob, em_pT, obvs, out, N);
}

// Round 3
// 1541.323 us; speedup vs baseline: 1.1949x; 1.1949x over previous
//
#include <hip/hip_runtime.h>
#include <cmath>

#define S       65
#define SP      68              // padded row stride (floats), 272 B (16B-aligned rows)
#define REC     (S*SP)          // 4420 floats per matrix record (16B-multiple)
#define F4      (REC/4)         // 1105 float4s
#define VOCAB   1024
#define EMS     68              // em_pT row stride
#define NTH     256
#define RT      5               // rows per thread tile
#define CT      4               // cols per thread tile (float4)
#define PSEG    768             // segment blocks (3 per CU)
#define GROUP   12
#define NGROUPS (PSEG/GROUP)    // 64

__device__ __forceinline__ float wave_max(float v) {
  #pragma unroll
  for (int o = 32; o > 0; o >>= 1) v = fmaxf(v, __shfl_xor(v, o));
  return v;
}
__device__ __forceinline__ float wave_sumf(float v) {
  #pragma unroll
  for (int o = 32; o > 0; o >>= 1) v += __shfl_xor(v, o);
  return v;
}
__device__ __forceinline__ int wave_sumi(int v) {
  #pragma unroll
  for (int o = 32; o > 0; o >>= 1) v += __shfl_xor(v, o);
  return v;
}

// async global->LDS, 16B per lane; LDS dest = wave-uniform base + lane*16
__device__ __forceinline__ void gld16(const float4* g, float4* l) {
  __builtin_amdgcn_global_load_lds(
      (const __attribute__((address_space(1))) unsigned int*)g,
      (__attribute__((address_space(3))) unsigned int*)l, 16, 0, 0);
}

// 65x65(x68-col) fp32 matmul tile: thread computes RT x CT outputs.
// All LDS reads are aligned float4 at thread-base + compile-time offset.
__device__ __forceinline__ void mm_tile(const float* Rl, const float* Cl,
                                        int r0, int c0, float acc[RT][CT]) {
  const float* rp = Rl + r0 * SP;
  const float* cp = Cl + c0;
  #pragma unroll
  for (int jb = 0; jb < 16; ++jb) {
    float4 cv4[4];
    float4 rv4[RT];
    #pragma unroll
    for (int k = 0; k < 4; ++k) cv4[k] = *(const float4*)(cp + (4*jb + k) * SP);
    #pragma unroll
    for (int q = 0; q < RT; ++q) rv4[q] = *(const float4*)(rp + q * SP + 4*jb);
    #pragma unroll
    for (int q = 0; q < RT; ++q) {
      const float rr[4] = {rv4[q].x, rv4[q].y, rv4[q].z, rv4[q].w};
      #pragma unroll
      for (int k = 0; k < 4; ++k) {
        const float cc[4] = {cv4[k].x, cv4[k].y, cv4[k].z, cv4[k].w};
        #pragma unroll
        for (int u = 0; u < CT; ++u)
          acc[q][u] = fmaf(rr[k], cc[u], acc[q][u]);
      }
    }
  }
  { // tail j = 64
    const float4 c4 = *(const float4*)(cp + 64 * SP);
    const float cc[4] = {c4.x, c4.y, c4.z, c4.w};
    #pragma unroll
    for (int q = 0; q < RT; ++q) {
      float rr = rp[q * SP + 64];
      #pragma unroll
      for (int u = 0; u < CT; ++u) acc[q][u] = fmaf(rr, cc[u], acc[q][u]);
    }
  }
}

// ---------- K1a: row softmax of log_trans -> transition probs a_prob[65][SP]
__global__ void k_trans_prep(const float* __restrict__ lt, float* __restrict__ a_prob) {
  int i = blockIdx.x, t = threadIdx.x;           // 64 threads, one wave
  float x0 = lt[i*S + t];
  float x1 = (t == 0) ? lt[i*S + 64] : -1e30f;
  float m = wave_max(fmaxf(x0, x1));
  float e0 = expf(x0 - m);
  float e1 = (t == 0) ? expf(x1 - m) : 0.f;
  float ssum = wave_sumf(e0 + e1);
  float inv = 1.f / ssum;
  a_prob[i*SP + t] = e0 * inv;
  if (t == 0) a_prob[i*SP + 64] = e1 * inv;
  if (t < 3)  a_prob[i*SP + 65 + t] = 0.f;       // zero pad cols
}

// ---------- K1b: row softmax of log_em -> em_pT[v][j] (transposed), stride EMS
__global__ __launch_bounds__(NTH) void k_em_prep(const float* __restrict__ le,
                                                 float* __restrict__ em_pT) {
  int j = blockIdx.x, t = threadIdx.x;
  const float* row = le + (size_t)j * VOCAB;
  float x[4];
  float m = -1e30f;
  #pragma unroll
  for (int q = 0; q < 4; ++q) { x[q] = row[t + 256*q]; m = fmaxf(m, x[q]); }
  m = wave_max(m);
  __shared__ float wred[4], wsum[4];
  int w = t >> 6, lane = t & 63;
  if (lane == 0) wred[w] = m;
  __syncthreads();
  m = fmaxf(fmaxf(wred[0], wred[1]), fmaxf(wred[2], wred[3]));
  float s = 0.f;
  #pragma unroll
  for (int q = 0; q < 4; ++q) s += expf(x[q] - m);
  s = wave_sumf(s);
  if (lane == 0) wsum[w] = s;
  __syncthreads();
  float inv = 1.f / (wsum[0] + wsum[1] + wsum[2] + wsum[3]);
  #pragma unroll
  for (int q = 0; q < 4; ++q)
    em_pT[(size_t)(t + 256*q) * EMS + j] = expf(x[q] - m) * inv;
}

// ---------- K2: pair table C_v = A * diag(e_v) * A   (1024 blocks)
__global__ __launch_bounds__(NTH) void k_pair(const float* __restrict__ a_prob,
                                              const float* __restrict__ em_pT,
                                              float* __restrict__ Ctab) {
  __shared__ __align__(16) float aL[REC];
  __shared__ __align__(16) float bL[REC];
  int v = blockIdx.x, t = threadIdx.x;
  {
    const float4* src = (const float4*)a_prob;
    float4* dst = (float4*)aL;
    for (int u = t; u < F4; u += NTH) dst[u] = src[u];
  }
  __syncthreads();
  for (int u = t; u < REC; u += NTH) {
    int j = u / SP;
    bL[u] = em_pT[(size_t)v * EMS + j] * aL[u];
  }
  __syncthreads();
  int rt = t / 17, ct = t % 17;
  bool act = rt < 13;
  int r0 = act ? rt * RT : 0;
  int c0 = ct * CT;
  float acc[RT][CT] = {};
  mm_tile(aL, bL, r0, c0, acc);
  float* dst = Ctab + (size_t)v * REC;
  if (act) {
    #pragma unroll
    for (int q = 0; q < RT; ++q) {
      float4 o; o.x = acc[q][0]; o.y = acc[q][1]; o.z = acc[q][2]; o.w = acc[q][3];
      *(float4*)(dst + (r0+q)*SP + c0) = o;   // pad cols come out exactly 0
    }
  }
}

// ---------- K3: segment chain product, async-LDS prefetch, in-place R update
__global__ __launch_bounds__(NTH, 3) void k_seg(const float* __restrict__ Ctab,
    const float* __restrict__ em_pT, const int* __restrict__ obvs,
    float* __restrict__ Rseg, int* __restrict__ eacc_out, int NP) {
  __shared__ __align__(16) float Rbuf[REC];
  __shared__ __align__(16) float Cbuf[2][REC];
  __shared__ float evb[2][SP];
  __shared__ int smax[2];

  const int p = blockIdx.x, t = threadIdx.x;
  const int base = NP / PSEG, rem = NP % PSEG;
  const int k0 = p*base + (p < rem ? p : rem);
  const int L  = base + (p < rem ? 1 : 0);
  const int rt = t / 17, ct = t % 17;
  const bool act = rt < 13;
  const int r0 = act ? rt * RT : 0;            // clamped: all reads in-bounds
  const int c0 = ct * CT;

  for (int u = t; u < REC; u += NTH) {
    int j = u / SP, k = u - j*SP;
    Rbuf[u] = (j == k) ? 1.f : 0.f;            // identity, zero pads
  }
  if (t == 0) { smax[0] = 0; smax[1] = 0; }
  if (L > 0) {
    int o1 = obvs[1 + 2*k0], o2 = obvs[2 + 2*k0];
    const float4* src = (const float4*)(Ctab + (size_t)o1 * REC);
    float4* dst = (float4*)(Cbuf[0]);
    #pragma unroll
    for (int q = 0; q < 5; ++q) {
      int u = t + q*NTH;
      if (u < F4) gld16(src + u, dst + u);
    }
    float ev0 = (t < S) ? em_pT[(size_t)o2 * EMS + t] : 0.f;
    if (t < SP) evb[0][t] = ev0;
  }
  __syncthreads();                             // drains vmcnt: Cbuf[0] ready

  int ci = 0;
  int my_eacc = 0;
  float scale = 1.f;
  for (int s = 0; s < L; ++s) {
    // deferred scale: previous step's block max, folded into this step's ev mult
    if (s > 0) {
      int bm = smax[(s-1) & 1];
      int e = (bm >> 23) - 127;
      my_eacc += e;
      scale = __int_as_float((127 - e) << 23);  // exact 2^-e
    }
    // async prefetch next C directly into the other LDS buffer (no regs held)
    int kn = k0 + s + 1; if (kn > NP - 1) kn = NP - 1;
    int o1n = obvs[1 + 2*kn], o2n = obvs[2 + 2*kn];
    {
      const float4* src = (const float4*)(Ctab + (size_t)o1n * REC);
      float4* dst = (float4*)(Cbuf[ci ^ 1]);
      #pragma unroll
      for (int q = 0; q < 5; ++q) {
        int u = t + q*NTH;
        if (u < F4) gld16(src + u, dst + u);
      }
    }
    float evreg = (t < S) ? em_pT[(size_t)o2n * EMS + t] : 0.f;

    // matmul acc = R * C
    float acc[RT][CT] = {};
    mm_tile(Rbuf, Cbuf[ci], r0, c0, acc);

    // block max of acc (pre-emission) for next step's rescale
    float mx = 0.f;
    if (act) {
      #pragma unroll
      for (int q = 0; q < RT; ++q)
        #pragma unroll
        for (int u = 0; u < CT; ++u) mx = fmaxf(mx, acc[q][u]);
    }
    mx = wave_max(mx);
    if ((t & 63) == 0) atomicMax(&smax[s & 1], __float_as_int(mx));
    __syncthreads();                 // barrier A: all reads of Rbuf/Cbuf[ci] done

    if (t < SP) evb[(s+1) & 1][t] = evreg;
    if (t == 0) smax[(s+1) & 1] = 0;           // reset slot for step s+1
    if (act) {                                 // in-place: old R is dead now
      float4 ev4 = *(const float4*)(&evb[s & 1][c0]);
      const float evs[4] = {ev4.x*scale, ev4.y*scale, ev4.z*scale, ev4.w*scale};
      float* rdst = Rbuf + r0*SP + c0;
      #pragma unroll
      for (int q = 0; q < RT; ++q) {
        float4 o;
        o.x = acc[q][0]*evs[0]; o.y = acc[q][1]*evs[1];
        o.z = acc[q][2]*evs[2]; o.w = acc[q][3]*evs[3];
        *(float4*)(rdst + q*SP) = o;
      }
    }
    __syncthreads();                 // barrier B: R_new visible, prefetch drained
    ci ^= 1;
  }

  { // write out; last step's max never applied (and never counted) — exact bookkeeping
    const float4* src = (const float4*)Rbuf;
    float4* dst = (float4*)(Rseg + (size_t)p * REC);
    for (int u = t; u < F4; u += NTH) dst[u] = src[u];
  }
  if (t == 0) eacc_out[p] = my_eacc;
}

// ---------- K4: chain 12 consecutive segment matrices per block
__global__ __launch_bounds__(NTH) void k_chain(const float* __restrict__ Rseg,
    float* __restrict__ Rm, int* __restrict__ eacc2) {
  __shared__ __align__(16) float Rb[2][REC];
  __shared__ __align__(16) float Cb[REC];
  __shared__ int smax[2];
  const int g = blockIdx.x, t = threadIdx.x;
  const int rt = t / 17, ct = t % 17;
  const bool act = rt < 13;
  const int r0 = act ? rt * RT : 0;
  const int c0 = ct * CT;
  {
    const float4* src = (const float4*)(Rseg + (size_t)(g*GROUP) * REC);
    float4* dst = (float4*)(Rb[0]);
    for (int u = t; u < F4; u += NTH) dst[u] = src[u];
  }
  if (t == 0) { smax[0] = 0; smax[1] = 0; }
  __syncthreads();
  int cur = 0, my_e = 0;
  for (int q2 = 1; q2 < GROUP; ++q2) {
    const float4* src = (const float4*)(Rseg + (size_t)(g*GROUP + q2) * REC);
    float4* dstc = (float4*)Cb;
    for (int u = t; u < F4; u += NTH) dstc[u] = src[u];
    __syncthreads();                          // B1
    float acc[RT][CT] = {};
    mm_tile(Rb[cur], Cb, r0, c0, acc);
    float mx = 0.f;
    if (act) {
      #pragma unroll
      for (int q = 0; q < RT; ++q)
        #pragma unroll
        for (int u = 0; u < CT; ++u) mx = fmaxf(mx, acc[q][u]);
    }
    mx = wave_max(mx);
    if ((t & 63) == 0) atomicMax(&smax[q2 & 1], __float_as_int(mx));
    __syncthreads();                          // B2
    int bm = smax[q2 & 1];
    int e = (bm >> 23) - 127;
    float scale = __int_as_float((127 - e) << 23);
    my_e += e;
    if (t == 0) smax[(q2+1) & 1] = 0;
    if (act) {
      float* rdst = Rb[cur ^ 1] + r0*SP + c0;
      #pragma unroll
      for (int q = 0; q < RT; ++q) {
        float4 o;
        o.x = acc[q][0]*scale; o.y = acc[q][1]*scale;
        o.z = acc[q][2]*scale; o.w = acc[q][3]*scale;
        *(float4*)(rdst + q*SP) = o;
      }
    }
    __syncthreads();
    cur ^= 1;
  }
  {
    const float4* src = (const float4*)(Rb[cur]);
    float4* dst = (float4*)(Rm + (size_t)g * REC);
    for (int u = t; u < F4; u += NTH) dst[u] = src[u];
  }
  if (t == 0) eacc2[g] = my_e;
}

// ---------- K5: final vector sweep + termination + log (single block)
__global__ __launch_bounds__(NTH) void k_final(const float* __restrict__ Rm,
    const float* __restrict__ lt, const int* __restrict__ e1, const int* __restrict__ e2,
    const float* __restrict__ a_prob, const float* __restrict__ em_pT,
    const int* __restrict__ obvs, float* __restrict__ out, int N) {
  __shared__ __align__(16) float Mb[2][REC];
  __shared__ float vL[SP];
  __shared__ float prod[SP];
  __shared__ int smax[2];
  __shared__ int esum_s;
  const int t = threadIdx.x, lane = t & 63;
  if (t == 0) { esum_s = 0; smax[0] = 0; smax[1] = 0; }
  if (t < S) vL[t] = (t == 0) ? 1.f : expf(-20.0f);   // exp(log_pi)
  {
    const float4* src = (const float4*)Rm;
    float4* dst = (float4*)(Mb[0]);
    for (int u = t; u < F4; u += NTH) dst[u] = src[u];
  }
  __syncthreads();
  {
    int es = 0;
    for (int u = t; u < PSEG; u += NTH) es += e1[u];
    for (int u = t; u < NGROUPS; u += NTH) es += e2[u];
    es = wave_sumi(es);
    if (lane == 0) atomicAdd(&esum_s, es);
  }
  int cur = 0, my_e = 0;
  for (int m = 0; m < NGROUPS; ++m) {
    if (m + 1 < NGROUPS) {
      const float4* src = (const float4*)(Rm + (size_t)(m+1) * REC);
      float4* dst = (float4*)(Mb[cur ^ 1]);
      for (int u = t; u < F4; u += NTH) dst[u] = src[u];
    }
    float acc = 0.f;
    if (t < S) {
      const float* Mp = Mb[cur];
      #pragma unroll 5
      for (int i = 0; i < S; ++i) acc = fmaf(vL[i], Mp[i*SP + t], acc);
    }
    float mx = (t < S) ? acc : 0.f;
    mx = wave_max(mx);
    if (lane == 0) atomicMax(&smax[m & 1], __float_as_int(mx));
    __syncthreads();                          // (1)
    int bm = smax[m & 1];
    int e = (bm >> 23) - 127;
    float scale = __int_as_float((127 - e) << 23);
    my_e += e;
    if (t == 0) smax[(m+1) & 1] = 0;
    if (t < S) vL[t] = acc * scale;
    __syncthreads();                          // (2)
    cur ^= 1;
  }
  if (N & 1) {                                // leftover unpaired step
    int oN = obvs[N];
    float acc2 = 0.f;
    if (t < S) {
      #pragma unroll 5
      for (int i = 0; i < S; ++i) acc2 = fmaf(vL[i], a_prob[i*SP + t], acc2);
      acc2 *= em_pT[(size_t)oN * EMS + t];
    }
    __syncthreads();
    if (t < S) vL[t] = acc2;
    __syncthreads();
  }
  if (t < S) prod[t] = vL[t] * expf(lt[t*S]);  // raw log_trans[:,0]
  __syncthreads();
  if (t == 0) {
    double z = 0.0;
    for (int i = 0; i < S; ++i) z += (double)prod[i];
    double logz = log(z) + (double)(esum_s + my_e) * 0.69314718055994530942;
    out[0] = (float)logz;
  }
}

extern "C" void kernel_launch(void* const* d_in, const int* in_sizes, int n_in,
                              void* d_out, int out_size, void* d_ws, size_t ws_size,
                              hipStream_t stream) {
  (void)n_in; (void)out_size;
  const int*   obvs = (const int*)d_in[0];
  const float* lt   = (const float*)d_in[1];
  const float* le   = (const float*)d_in[2];
  float* out = (float*)d_out;
  const int T  = in_sizes[0];
  const int N  = T - 2;          // scan length
  const int NP = N >> 1;         // pair count

  float* ws = (float*)d_ws;
  size_t off = 0;
  float* a_prob = ws + off; off += REC;                     // 4420
  float* em_pT  = ws + off; off += (size_t)VOCAB * EMS;     // 69632
  float* Ctab   = ws + off; off += (size_t)VOCAB * REC;     // 4,526,080
  float* Rseg   = ws + off; off += (size_t)PSEG * REC;      // 3,394,560
  float* Rm     = ws + off; off += (size_t)NGROUPS * REC;   // 282,880
  int* e1 = (int*)(ws + off); off += PSEG;
  int* e2 = (int*)(ws + off); off += NGROUPS;
  if (ws_size < off * sizeof(float)) return;                // ~33.1 MiB needed

  k_trans_prep<<<dim3(S), dim3(64), 0, stream>>>(lt, a_prob);
  k_em_prep  <<<dim3(S), dim3(NTH), 0, stream>>>(le, em_pT);
  k_pair     <<<dim3(VOCAB), dim3(NTH), 0, stream>>>(a_prob, em_pT, Ctab);
  k_seg      <<<dim3(PSEG), dim3(NTH), 0, stream>>>(Ctab, em_pT, obvs, Rseg, e1, NP);
  k_chain    <<<dim3(NGROUPS), dim3(NTH), 0, stream>>>(Rseg, Rm, e2);
  k_final    <<<dim3(1), dim3(NTH), 0, stream>>>(Rm, lt, e1, e2, a_prob, em_pT, obvs, out, N);
}

// Round 5
// 846.842 us; speedup vs baseline: 2.1748x; 1.8201x over previous
//
#include <hip/hip_runtime.h>
#include <cmath>

#define S       65
#define SP      68              // fp32 padded row stride
#define REC     (S*SP)          // 4420 floats per fp32 matrix record
#define F4      (REC/4)
#define VOCAB   1024
#define EMS     68
#define NTH     256
#define RT      5
#define CT      4
#define PSEG    768
#define GROUP   12
#define NGROUPS (PSEG/GROUP)

// bf16 frag table record: h-frags 8KB | l-frags 8KB | row64 f32[72] | col64 f32[72]
#define ATS     16960           // bytes per table record (64B multiple)
#define A_R64   16384
#define A_C64   16672

typedef __attribute__((ext_vector_type(8))) short bf16x8;
typedef __attribute__((ext_vector_type(4))) float f32x4;
#define MFMA(a,b,c) __builtin_amdgcn_mfma_f32_16x16x32_bf16(a,b,c,0,0,0)

__device__ __forceinline__ float wave_max(float v) {
  #pragma unroll
  for (int o = 32; o > 0; o >>= 1) v = fmaxf(v, __shfl_xor(v, o));
  return v;
}
__device__ __forceinline__ float wave_sumf(float v) {
  #pragma unroll
  for (int o = 32; o > 0; o >>= 1) v += __shfl_xor(v, o);
  return v;
}
__device__ __forceinline__ int wave_sumi(int v) {
  #pragma unroll
  for (int o = 32; o > 0; o >>= 1) v += __shfl_xor(v, o);
  return v;
}
__device__ __forceinline__ unsigned short f2bf(float x) {  // RNE (unbiased!)
  unsigned u = __float_as_uint(x);
  return (unsigned short)((u + 0x7fffu + ((u >> 16) & 1u)) >> 16);
}
__device__ __forceinline__ unsigned short tbf(float x) {   // truncate (lo term)
  return (unsigned short)(__float_as_uint(x) >> 16);
}
__device__ __forceinline__ float bf2f(unsigned short h) {
  return __uint_as_float(((unsigned)h) << 16);
}
__device__ __forceinline__ float blo(unsigned h, unsigned lw) {
  return __uint_as_float(h << 16) + __uint_as_float(lw << 16);
}
__device__ __forceinline__ float bhi(unsigned h, unsigned lw) {
  return __uint_as_float(h & 0xffff0000u) + __uint_as_float(lw & 0xffff0000u);
}
__device__ __forceinline__ void gld16(const float4* g, float4* l) {
  __builtin_amdgcn_global_load_lds(
      (const __attribute__((address_space(1))) unsigned int*)g,
      (__attribute__((address_space(3))) unsigned int*)l, 16, 0, 0);
}

// fp32 65x65 tile matmul (used by k_pair / k_chain)
__device__ __forceinline__ void mm_tile(const float* Rl, const float* Cl,
                                        int r0, int c0, float acc[RT][CT]) {
  const float* rp = Rl + r0 * SP;
  const float* cp = Cl + c0;
  #pragma unroll
  for (int jb = 0; jb < 16; ++jb) {
    float4 cv4[4]; float4 rv4[RT];
    #pragma unroll
    for (int k = 0; k < 4; ++k) cv4[k] = *(const float4*)(cp + (4*jb + k) * SP);
    #pragma unroll
    for (int q = 0; q < RT; ++q) rv4[q] = *(const float4*)(rp + q * SP + 4*jb);
    #pragma unroll
    for (int q = 0; q < RT; ++q) {
      const float rr[4] = {rv4[q].x, rv4[q].y, rv4[q].z, rv4[q].w};
      #pragma unroll
      for (int k = 0; k < 4; ++k) {
        const float cc[4] = {cv4[k].x, cv4[k].y, cv4[k].z, cv4[k].w};
        #pragma unroll
        for (int u = 0; u < CT; ++u) acc[q][u] = fmaf(rr[k], cc[u], acc[q][u]);
      }
    }
  }
  { const float4 c4 = *(const float4*)(cp + 64 * SP);
    const float cc[4] = {c4.x, c4.y, c4.z, c4.w};
    #pragma unroll
    for (int q = 0; q < RT; ++q) {
      float rr = rp[q * SP + 64];
      #pragma unroll
      for (int u = 0; u < CT; ++u) acc[q][u] = fmaf(rr, cc[u], acc[q][u]);
    } }
}

// ---------- K1a: softmax(log_trans) -> a_prob[65][SP]
__global__ void k_trans_prep(const float* __restrict__ lt, float* __restrict__ a_prob) {
  int i = blockIdx.x, t = threadIdx.x;
  float x0 = lt[i*S + t];
  float x1 = (t == 0) ? lt[i*S + 64] : -1e30f;
  float m = wave_max(fmaxf(x0, x1));
  float e0 = expf(x0 - m);
  float e1 = (t == 0) ? expf(x1 - m) : 0.f;
  float inv = 1.f / wave_sumf(e0 + e1);
  a_prob[i*SP + t] = e0 * inv;
  if (t == 0) a_prob[i*SP + 64] = e1 * inv;
  if (t < 3)  a_prob[i*SP + 65 + t] = 0.f;
}

// ---------- K1b: softmax(log_em) -> em_pT[v][j] transposed
__global__ __launch_bounds__(NTH) void k_em_prep(const float* __restrict__ le,
                                                 float* __restrict__ em_pT) {
  int j = blockIdx.x, t = threadIdx.x;
  const float* row = le + (size_t)j * VOCAB;
  float x[4]; float m = -1e30f;
  #pragma unroll
  for (int q = 0; q < 4; ++q) { x[q] = row[t + 256*q]; m = fmaxf(m, x[q]); }
  m = wave_max(m);
  __shared__ float wred[4], wsum[4];
  int w = t >> 6, lane = t & 63;
  if (lane == 0) wred[w] = m;
  __syncthreads();
  m = fmaxf(fmaxf(wred[0], wred[1]), fmaxf(wred[2], wred[3]));
  float s = 0.f;
  #pragma unroll
  for (int q = 0; q < 4; ++q) s += expf(x[q] - m);
  s = wave_sumf(s);
  if (lane == 0) wsum[w] = s;
  __syncthreads();
  float inv = 1.f / (wsum[0] + wsum[1] + wsum[2] + wsum[3]);
  #pragma unroll
  for (int q = 0; q < 4; ++q)
    em_pT[(size_t)(t + 256*q) * EMS + j] = expf(x[q] - m) * inv;
}

// ---------- K2: C_v = A*diag(e_v)*A, emitted TRANSPOSED as bf16 h/l frags + f32 borders
__global__ __launch_bounds__(NTH) void k_pair(const float* __restrict__ a_prob,
                                              const float* __restrict__ em_pT,
                                              char* __restrict__ Ctab) {
  __shared__ __align__(16) float aL[REC];
  __shared__ __align__(16) float bL[REC];
  __shared__ __align__(16) float cL[REC];
  int v = blockIdx.x, t = threadIdx.x;
  { const float4* src = (const float4*)a_prob; float4* dst = (float4*)aL;
    for (int u = t; u < F4; u += NTH) dst[u] = src[u]; }
  __syncthreads();
  for (int u = t; u < REC; u += NTH) {
    int j = u / SP;
    bL[u] = em_pT[(size_t)v * EMS + j] * aL[u];
  }
  __syncthreads();
  int rt = t / 17, ct = t % 17;
  bool act = rt < 13;
  int r0 = act ? rt * RT : 0;
  int c0 = ct * CT;
  float acc[RT][CT] = {};
  mm_tile(aL, bL, r0, c0, acc);
  if (act) {
    #pragma unroll
    for (int q = 0; q < RT; ++q) {
      float4 o; o.x = acc[q][0]; o.y = acc[q][1]; o.z = acc[q][2]; o.w = acc[q][3];
      *(float4*)(cL + (r0+q)*SP + c0) = o;
    }
  }
  __syncthreads();
  char* Cv = Ctab + (size_t)v * ATS;
  // frag chunks: c<512 -> h at c*16; c>=512 -> l at c*16 (=8192+..)
  for (int c = t; c < 1024; c += NTH) {
    int hl = c >> 9, r = c & 511;
    int mi = r >> 7, ks = (r >> 6) & 1, ln = r & 63;
    int row = 16*mi + (ln & 15);          // A row (= C col, table is transposed)
    int kb = 32*ks + 8*(ln >> 4);
    unsigned wd[4];
    #pragma unroll
    for (int eo = 0; eo < 4; ++eo) {
      float x0 = cL[(kb + 2*eo    )*SP + row];   // A[row][k] = C[k][row]
      float x1 = cL[(kb + 2*eo + 1)*SP + row];
      unsigned short b0, b1;
      if (hl == 0) { b0 = f2bf(x0); b1 = f2bf(x1); }
      else {
        unsigned short h0 = f2bf(x0), h1 = f2bf(x1);
        b0 = tbf(x0 - bf2f(h0)); b1 = tbf(x1 - bf2f(h1));
      }
      wd[eo] = (unsigned)b0 | ((unsigned)b1 << 16);
    }
    uint4 o; o.x = wd[0]; o.y = wd[1]; o.z = wd[2]; o.w = wd[3];
    *(uint4*)(Cv + c*16) = o;
  }
  if (t < 72) {
    float r64 = (t < S) ? cL[t*SP + 64] : 0.f;   // T64[k]  = C[k][64]
    float c64 = (t < S) ? cL[64*SP + t] : 0.f;   // Tc64[i] = C[64][i]
    ((float*)(Cv + A_R64))[t] = r64;
    ((float*)(Cv + A_C64))[t] = c64;
  }
}

// ---------- K3: MFMA segment chain. State = S^T as bf16 h/l B-frags + f32 borders.
__global__ __launch_bounds__(NTH, 3) void k_seg(const char* __restrict__ Ctab,
    const float* __restrict__ em_pT, const int* __restrict__ obvs,
    float* __restrict__ Rseg, int* __restrict__ eacc_out, int NP) {
  __shared__ __align__(16) char Ab[2][ATS];
  __shared__ __align__(16) char Sf[16384];       // h: 0..8191, l: 8192..16383
  __shared__ __align__(16) float Srow64[72];
  __shared__ __align__(16) float Scol64[72];
  __shared__ __align__(16) float evb[2][72];
  __shared__ float Scorner;
  __shared__ int smax[2];

  const int p = blockIdx.x, t = threadIdx.x;
  const int w = t >> 6, l = t & 63;
  const int h4 = l >> 4, l15 = l & 15;
  const int miq = (w >> 1) * 2, niq = (w & 1) * 2;
  const int base = NP / PSEG, rem = NP % PSEG;
  const int k0 = p*base + (p < rem ? p : rem);
  const int L  = base + (p < rem ? 1 : 0);

  for (int u = t; u < 1024; u += NTH) ((float4*)Sf)[u] = make_float4(0.f,0.f,0.f,0.f);
  if (t < 72) { Srow64[t] = 0.f; Scol64[t] = 0.f; }
  if (t == 0) { smax[0] = 0; smax[1] = 0; }
  __syncthreads();
  if (t < 64) {  // identity diagonal (h = bf16 1.0)
    int blk = (t >> 4)*2 + (t >> 5);
    int ln  = (t & 15) + 16*((t & 31) >> 3);
    *(unsigned short*)(Sf + blk*1024 + ln*16 + (t & 7)*2) = 0x3F80;
  }
  if (t == 0) Scorner = 1.f;
  {
    int o1 = obvs[1 + 2*k0], o2 = obvs[2 + 2*k0];
    const float4* src = (const float4*)(Ctab + (size_t)o1 * ATS);
    float4* dst = (float4*)(Ab[0]);
    #pragma unroll
    for (int q = 0; q < 5; ++q) { int u = t + q*NTH; if (u < ATS/16) gld16(src+u, dst+u); }
    if (t < 72) evb[0][t] = (t < S) ? em_pT[(size_t)o2 * EMS + t] : 0.f;
  }
  __syncthreads();

  int ci = 0, my_e = 0;
  float scale = 1.f;
  for (int s = 0; s < L; ++s) {
    const int sb = s & 1;
    if (s > 0) {
      int bm = smax[sb ^ 1];
      int e = (bm >> 23) - 127;
      my_e += e;
      scale = __int_as_float((127 - e) << 23);
    }
    // prefetch next table record + ev
    int kn = k0 + s + 1; if (kn > NP - 1) kn = NP - 1;
    int o1n = obvs[1 + 2*kn], o2n = obvs[2 + 2*kn];
    { const float4* src = (const float4*)(Ctab + (size_t)o1n * ATS);
      float4* dst = (float4*)(Ab[ci ^ 1]);
      #pragma unroll
      for (int q = 0; q < 5; ++q) { int u = t + q*NTH; if (u < ATS/16) gld16(src+u, dst+u); } }
    float evreg = (t < S) ? em_pT[(size_t)o2n * EMS + t] : 0.f;

    const char* A = Ab[ci];
    const float* T64  = (const float*)(A + A_R64);
    const float* Tc64 = (const float*)(A + A_C64);

    // interior MFMA: P = C^T * S^T, 64x64 in 4 16x16 tiles per wave
    f32x4 acc00 = {0.f,0.f,0.f,0.f}, acc01 = acc00, acc10 = acc00, acc11 = acc00;
    #pragma unroll
    for (int ks = 0; ks < 2; ++ks) {
      bf16x8 ah0 = *(const bf16x8*)(A + ((miq  )*2+ks)*1024 + l*16);
      bf16x8 ah1 = *(const bf16x8*)(A + ((miq+1)*2+ks)*1024 + l*16);
      bf16x8 al0 = *(const bf16x8*)(A + 8192 + ((miq  )*2+ks)*1024 + l*16);
      bf16x8 al1 = *(const bf16x8*)(A + 8192 + ((miq+1)*2+ks)*1024 + l*16);
      bf16x8 bh0 = *(const bf16x8*)(Sf + ((niq  )*2+ks)*1024 + l*16);
      bf16x8 bh1 = *(const bf16x8*)(Sf + ((niq+1)*2+ks)*1024 + l*16);
      bf16x8 bl0 = *(const bf16x8*)(Sf + 8192 + ((niq  )*2+ks)*1024 + l*16);
      bf16x8 bl1 = *(const bf16x8*)(Sf + 8192 + ((niq+1)*2+ks)*1024 + l*16);
      acc00 = MFMA(ah0, bh0, acc00); acc00 = MFMA(ah0, bl0, acc00); acc00 = MFMA(al0, bh0, acc00);
      acc01 = MFMA(ah0, bh1, acc01); acc01 = MFMA(ah0, bl1, acc01); acc01 = MFMA(al0, bh1, acc01);
      acc10 = MFMA(ah1, bh0, acc10); acc10 = MFMA(ah1, bl0, acc10); acc10 = MFMA(al1, bh0, acc10);
      acc11 = MFMA(ah1, bh1, acc11); acc11 = MFMA(ah1, bl1, acc11); acc11 = MFMA(al1, bh1, acc11);
    }

    // border pass R: wave w computes P[64][j], j = 16w+l15 (k interior via state frags)
    float pr = 0.f;
    #pragma unroll
    for (int ks = 0; ks < 2; ++ks) {
      uint4 hb = *(const uint4*)(Sf + (w*2+ks)*1024 + l*16);
      uint4 lb = *(const uint4*)(Sf + 8192 + (w*2+ks)*1024 + l*16);
      const float* tp = T64 + 32*ks + 8*h4;
      float4 ta = *(const float4*)tp, tb = *(const float4*)(tp + 4);
      pr += blo(hb.x,lb.x)*ta.x + bhi(hb.x,lb.x)*ta.y
          + blo(hb.y,lb.y)*ta.z + bhi(hb.y,lb.y)*ta.w
          + blo(hb.z,lb.z)*tb.x + bhi(hb.z,lb.z)*tb.y
          + blo(hb.w,lb.w)*tb.z + bhi(hb.w,lb.w)*tb.w;
    }
    pr += __shfl_xor(pr, 16); pr += __shfl_xor(pr, 32);
    pr += T64[64] * Srow64[16*w + l15];
    float ev64 = evb[sb][64];
    float nrow = ev64 * scale * pr;

    // border pass C: wave w computes P[i][64], i = 16w+l15 (via table frags x Scol64)
    float pc = 0.f;
    #pragma unroll
    for (int ks = 0; ks < 2; ++ks) {
      uint4 ha = *(const uint4*)(A + (w*2+ks)*1024 + l*16);
      uint4 la = *(const uint4*)(A + 8192 + (w*2+ks)*1024 + l*16);
      const float* sp2 = Scol64 + 32*ks + 8*h4;
      float4 sa = *(const float4*)sp2, sb2 = *(const float4*)(sp2 + 4);
      pc += blo(ha.x,la.x)*sa.x + bhi(ha.x,la.x)*sa.y
          + blo(ha.y,la.y)*sa.z + bhi(ha.y,la.y)*sa.w
          + blo(ha.z,la.z)*sb2.x + bhi(ha.z,la.z)*sb2.y
          + blo(ha.w,la.w)*sb2.z + bhi(ha.w,la.w)*sb2.w;
    }
    pc += __shfl_xor(pc, 16); pc += __shfl_xor(pc, 32);
    pc += Tc64[16*w + l15] * Scorner;
    float ncol = evb[sb][16*w + l15] * scale * pc;

    // corner P[64][64] (wave 3)
    float ncorner = 0.f;
    if (w == 3) {
      float pq = T64[l] * Scol64[l];
      pq = wave_sumf(pq);
      pq += T64[64] * Scorner;
      ncorner = ev64 * scale * pq;
    }

    // rank-1 (k=64) into interior: acc += Tc64[i] * Srow64[j]
    {
      float4 tc0 = *(const float4*)(Tc64 + 16*miq + 4*h4);
      float4 tc1 = *(const float4*)(Tc64 + 16*(miq+1) + 4*h4);
      float r0j = Srow64[16*niq + l15], r1j = Srow64[16*(niq+1) + l15];
      acc00.x += tc0.x*r0j; acc00.y += tc0.y*r0j; acc00.z += tc0.z*r0j; acc00.w += tc0.w*r0j;
      acc01.x += tc0.x*r1j; acc01.y += tc0.y*r1j; acc01.z += tc0.z*r1j; acc01.w += tc0.w*r1j;
      acc10.x += tc1.x*r0j; acc10.y += tc1.y*r0j; acc10.z += tc1.z*r0j; acc10.w += tc1.w*r0j;
      acc11.x += tc1.x*r1j; acc11.y += tc1.y*r1j; acc11.z += tc1.z*r1j; acc11.w += tc1.w*r1j;
    }
    // interior block max (pre-emission)
    float mx = fmaxf(fmaxf(fmaxf(acc00.x,acc00.y),fmaxf(acc00.z,acc00.w)),
               fmaxf(fmaxf(acc01.x,acc01.y),fmaxf(acc01.z,acc01.w)));
    mx = fmaxf(mx, fmaxf(fmaxf(fmaxf(acc10.x,acc10.y),fmaxf(acc10.z,acc10.w)),
                   fmaxf(fmaxf(acc11.x,acc11.y),fmaxf(acc11.z,acc11.w))));
    mx = wave_max(mx);
    if (l == 0) atomicMax(&smax[sb], __float_as_int(mx));

    __syncthreads();   // barrier A: all reads of state/table done; prefetch drained

    if (t < 72) evb[sb ^ 1][t] = evreg;
    if (t == 0) smax[sb ^ 1] = 0;
    if (l < 16) { Srow64[16*w + l15] = nrow; Scol64[16*w + l15] = ncol; }
    if (w == 3 && l == 0) Scorner = ncorner;
    {
      float4 ev0 = *(const float4*)(&evb[sb][16*miq + 4*h4]);
      float4 ev1 = *(const float4*)(&evb[sb][16*(miq+1) + 4*h4]);
      float e0x = ev0.x*scale, e0y = ev0.y*scale, e0z = ev0.z*scale, e0w = ev0.w*scale;
      float e1x = ev1.x*scale, e1y = ev1.y*scale, e1z = ev1.z*scale, e1w = ev1.w*scale;
      auto wb = [&](const f32x4& a, float sx, float sy, float sz, float sw, int mi, int ni) {
        float v0 = a.x*sx, v1 = a.y*sy, v2 = a.z*sz, v3 = a.w*sw;
        unsigned short h0=f2bf(v0), h1=f2bf(v1), h2=f2bf(v2), h3=f2bf(v3);
        unsigned hw0 = (unsigned)h0 | ((unsigned)h1<<16);
        unsigned hw1 = (unsigned)h2 | ((unsigned)h3<<16);
        unsigned short q0=tbf(v0-bf2f(h0)), q1=tbf(v1-bf2f(h1)),
                       q2=tbf(v2-bf2f(h2)), q3=tbf(v3-bf2f(h3));
        unsigned lw0 = (unsigned)q0 | ((unsigned)q1<<16);
        unsigned lw1 = (unsigned)q2 | ((unsigned)q3<<16);
        char* dst = Sf + (ni*2 + (mi>>1))*1024
                       + (l15 + 16*(2*(mi&1) + (h4>>1)))*16 + (h4&1)*8;
        *(uint2*)dst          = make_uint2(hw0, hw1);
        *(uint2*)(dst + 8192) = make_uint2(lw0, lw1);
      };
      wb(acc00, e0x,e0y,e0z,e0w, miq,   niq  );
      wb(acc01, e0x,e0y,e0z,e0w, miq,   niq+1);
      wb(acc10, e1x,e1y,e1z,e1w, miq+1, niq  );
      wb(acc11, e1x,e1y,e1z,e1w, miq+1, niq+1);
    }
    __syncthreads();   // barrier B: new state visible
    ci ^= 1;
  }

  // emit segment matrix (S^T) as compact fp32 [65][SP], zero pads
  for (int u = t; u < REC; u += NTH) {
    int k = u / SP, j = u - k*SP;
    float f = 0.f;
    if (j < S) {
      if (k == 64)      f = (j == 64) ? Scorner : Srow64[j];
      else if (j == 64) f = Scol64[k];
      else {
        int blk = (j >> 4)*2 + (k >> 5);
        int ln  = (j & 15) + 16*((k & 31) >> 3);
        const char* bp = Sf + blk*1024 + ln*16 + (k & 7)*2;
        unsigned hh = *(const unsigned short*)bp;
        unsigned ll = *(const unsigned short*)(bp + 8192);
        f = __uint_as_float(hh << 16) + __uint_as_float(ll << 16);
      }
    }
    Rseg[(size_t)p*REC + u] = f;
  }
  if (t == 0) eacc_out[p] = my_e;
}

// ---------- K4: chain 12 transposed segments: T <- G_q * T (ascending q)
__global__ __launch_bounds__(NTH) void k_chain(const float* __restrict__ Rseg,
    float* __restrict__ Rm, int* __restrict__ eacc2) {
  __shared__ __align__(16) float Rb[2][REC];
  __shared__ __align__(16) float Cb[REC];
  __shared__ int smax[2];
  const int g = blockIdx.x, t = threadIdx.x;
  const int rt = t / 17, ct = t % 17;
  const bool act = rt < 13;
  const int r0 = act ? rt * RT : 0;
  const int c0 = ct * CT;
  { const float4* src = (const float4*)(Rseg + (size_t)(g*GROUP) * REC);
    float4* dst = (float4*)(Rb[0]);
    for (int u = t; u < F4; u += NTH) dst[u] = src[u]; }
  if (t == 0) { smax[0] = 0; smax[1] = 0; }
  __syncthreads();
  int cur = 0, my_e = 0;
  for (int q2 = 1; q2 < GROUP; ++q2) {
    { const float4* src = (const float4*)(Rseg + (size_t)(g*GROUP + q2) * REC);
      float4* dst = (float4*)Cb;
      for (int u = t; u < F4; u += NTH) dst[u] = src[u]; }
    __syncthreads();
    float acc[RT][CT] = {};
    mm_tile(Cb, Rb[cur], r0, c0, acc);      // left-multiply: new = G_q * T
    float mx = 0.f;
    if (act) {
      #pragma unroll
      for (int q = 0; q < RT; ++q)
        #pragma unroll
        for (int u = 0; u < CT; ++u) mx = fmaxf(mx, acc[q][u]);
    }
    mx = wave_max(mx);
    if ((t & 63) == 0) atomicMax(&smax[q2 & 1], __float_as_int(mx));
    __syncthreads();
    int bm = smax[q2 & 1];
    int e = (bm >> 23) - 127;
    float scale = __int_as_float((127 - e) << 23);
    my_e += e;
    if (t == 0) smax[(q2+1) & 1] = 0;
    if (act) {
      float* rdst = Rb[cur ^ 1] + r0*SP + c0;
      #pragma unroll
      for (int q = 0; q < RT; ++q) {
        float4 o;
        o.x = acc[q][0]*scale; o.y = acc[q][1]*scale;
        o.z = acc[q][2]*scale; o.w = acc[q][3]*scale;
        *(float4*)(rdst + q*SP) = o;
      }
    }
    __syncthreads();
    cur ^= 1;
  }
  { const float4* src = (const float4*)(Rb[cur]);
    float4* dst = (float4*)(Rm + (size_t)g * REC);
    for (int u = t; u < F4; u += NTH) dst[u] = src[u]; }
  if (t == 0) eacc2[g] = my_e;
}

// ---------- K5: final sweep (group matrices are transposed: row-t dot)
__global__ __launch_bounds__(NTH) void k_final(const float* __restrict__ Rm,
    const float* __restrict__ lt, const int* __restrict__ e1, const int* __restrict__ e2,
    const float* __restrict__ a_prob, const float* __restrict__ em_pT,
    const int* __restrict__ obvs, float* __restrict__ out, int N) {
  __shared__ __align__(16) float Mb[2][REC];
  __shared__ float vL[SP];
  __shared__ float prod[SP];
  __shared__ int smax[2];
  __shared__ int esum_s;
  const int t = threadIdx.x, lane = t & 63;
  if (t == 0) { esum_s = 0; smax[0] = 0; smax[1] = 0; }
  if (t < S) vL[t] = (t == 0) ? 1.f : expf(-20.0f);
  { const float4* src = (const float4*)Rm;
    float4* dst = (float4*)(Mb[0]);
    for (int u = t; u < F4; u += NTH) dst[u] = src[u]; }
  __syncthreads();
  {
    int es = 0;
    for (int u = t; u < PSEG; u += NTH) es += e1[u];
    for (int u = t; u < NGROUPS; u += NTH) es += e2[u];
    es = wave_sumi(es);
    if (lane == 0) atomicAdd(&esum_s, es);
  }
  int cur = 0, my_e = 0;
  for (int m = 0; m < NGROUPS; ++m) {
    if (m + 1 < NGROUPS) {
      const float4* src = (const float4*)(Rm + (size_t)(m+1) * REC);
      float4* dst = (float4*)(Mb[cur ^ 1]);
      for (int u = t; u < F4; u += NTH) dst[u] = src[u];
    }
    float acc = 0.f;
    if (t < S) {
      const float* Mp = Mb[cur];
      #pragma unroll 5
      for (int i = 0; i < S; ++i) acc = fmaf(vL[i], Mp[t*SP + i], acc);  // row-t (transposed)
    }
    float mx = (t < S) ? acc : 0.f;
    mx = wave_max(mx);
    if (lane == 0) atomicMax(&smax[m & 1], __float_as_int(mx));
    __syncthreads();
    int bm = smax[m & 1];
    int e = (bm >> 23) - 127;
    float scale = __int_as_float((127 - e) << 23);
    my_e += e;
    if (t == 0) smax[(m+1) & 1] = 0;
    if (t < S) vL[t] = acc * scale;
    __syncthreads();
    cur ^= 1;
  }
  if (N & 1) {
    int oN = obvs[N];
    float acc2 = 0.f;
    if (t < S) {
      #pragma unroll 5
      for (int i = 0; i < S; ++i) acc2 = fmaf(vL[i], a_prob[i*SP + t], acc2);
      acc2 *= em_pT[(size_t)oN * EMS + t];
    }
    __syncthreads();
    if (t < S) vL[t] = acc2;
    __syncthreads();
  }
  if (t < S) prod[t] = vL[t] * expf(lt[t*S]);
  __syncthreads();
  if (t == 0) {
    double z = 0.0;
    for (int i = 0; i < S; ++i) z += (double)prod[i];
    double logz = log(z) + (double)(esum_s + my_e) * 0.69314718055994530942;
    out[0] = (float)logz;
  }
}

extern "C" void kernel_launch(void* const* d_in, const int* in_sizes, int n_in,
                              void* d_out, int out_size, void* d_ws, size_t ws_size,
                              hipStream_t stream) {
  (void)n_in; (void)out_size;
  const int*   obvs = (const int*)d_in[0];
  const float* lt   = (const float*)d_in[1];
  const float* le   = (const float*)d_in[2];
  float* out = (float*)d_out;
  const int T  = in_sizes[0];
  const int N  = T - 2;
  const int NP = N >> 1;

  float* ws = (float*)d_ws;
  size_t off = 0;
  float* a_prob = ws + off; off += REC;                       // 4420
  float* em_pT  = ws + off; off += (size_t)VOCAB * EMS;       // 69632
  char*  Ctab   = (char*)(ws + off); off += (size_t)VOCAB * (ATS/4);  // 4,341,760 floats
  float* Rseg   = ws + off; off += (size_t)PSEG * REC;        // 3,394,560
  float* Rm     = ws + off; off += (size_t)NGROUPS * REC;     // 282,880
  int* e1 = (int*)(ws + off); off += PSEG;
  int* e2 = (int*)(ws + off); off += NGROUPS;
  if (ws_size < off * sizeof(float)) return;                  // ~32.4 MiB

  k_trans_prep<<<dim3(S), dim3(64), 0, stream>>>(lt, a_prob);
  k_em_prep  <<<dim3(S), dim3(NTH), 0, stream>>>(le, em_pT);
  k_pair     <<<dim3(VOCAB), dim3(NTH), 0, stream>>>(a_prob, em_pT, Ctab);
  k_seg      <<<dim3(PSEG), dim3(NTH), 0, stream>>>(Ctab, em_pT, obvs, Rseg, e1, NP);
  k_chain    <<<dim3(NGROUPS), dim3(NTH), 0, stream>>>(Rseg, Rm, e2);
  k_final    <<<dim3(1), dim3(NTH), 0, stream>>>(Rm, lt, e1, e2, a_prob, em_pT, obvs, out, N);
}

// Round 7
// 638.754 us; speedup vs baseline: 2.8833x; 1.3258x over previous
//
#include <hip/hip_runtime.h>
#include <cmath>

#define S       65
#define SP      68              // fp32 padded row stride
#define REC     (S*SP)          // 4420 floats per fp32 matrix record
#define F4      (REC/4)
#define VOCAB   1024
#define EMS     68
#define NTH     256
#define RT      5
#define CT      4

// bf16 frag table record: h-frags 8KB | l-frags 8KB | row64 f32[72] | col64 f32[72]
#define ATS     16960           // bytes per table record (64B multiple)
#define A_R64   16384
#define A_C64   16672

typedef __attribute__((ext_vector_type(8))) short bf16x8;
typedef __attribute__((ext_vector_type(4))) float f32x4;
#define MFMA(a,b,c) __builtin_amdgcn_mfma_f32_16x16x32_bf16(a,b,c,0,0,0)

__device__ __forceinline__ float wave_max(float v) {
  #pragma unroll
  for (int o = 32; o > 0; o >>= 1) v = fmaxf(v, __shfl_xor(v, o));
  return v;
}
__device__ __forceinline__ float wave_sumf(float v) {
  #pragma unroll
  for (int o = 32; o > 0; o >>= 1) v += __shfl_xor(v, o);
  return v;
}
__device__ __forceinline__ int wave_sumi(int v) {
  #pragma unroll
  for (int o = 32; o > 0; o >>= 1) v += __shfl_xor(v, o);
  return v;
}
__device__ __forceinline__ unsigned short f2bf(float x) {  // RNE (unbiased!)
  unsigned u = __float_as_uint(x);
  return (unsigned short)((u + 0x7fffu + ((u >> 16) & 1u)) >> 16);
}
__device__ __forceinline__ unsigned short tbf(float x) {   // truncate (lo term)
  return (unsigned short)(__float_as_uint(x) >> 16);
}
__device__ __forceinline__ float bf2f(unsigned short h) {
  return __uint_as_float(((unsigned)h) << 16);
}
__device__ __forceinline__ float blo(unsigned h, unsigned lw) {
  return __uint_as_float(h << 16) + __uint_as_float(lw << 16);
}
__device__ __forceinline__ float bhi(unsigned h, unsigned lw) {
  return __uint_as_float(h & 0xffff0000u) + __uint_as_float(lw & 0xffff0000u);
}
__device__ __forceinline__ uint4 asu4(bf16x8 v) {
  union { bf16x8 b; uint4 u; } x; x.b = v; return x.u;
}
__device__ __forceinline__ void gld16(const float4* g, float4* l) {
  __builtin_amdgcn_global_load_lds(
      (const __attribute__((address_space(1))) unsigned int*)g,
      (__attribute__((address_space(3))) unsigned int*)l, 16, 0, 0);
}

// fp32 65x65 tile matmul (used by k_pair / k_chain)
__device__ __forceinline__ void mm_tile(const float* Rl, const float* Cl,
                                        int r0, int c0, float acc[RT][CT]) {
  const float* rp = Rl + r0 * SP;
  const float* cp = Cl + c0;
  #pragma unroll
  for (int jb = 0; jb < 16; ++jb) {
    float4 cv4[4]; float4 rv4[RT];
    #pragma unroll
    for (int k = 0; k < 4; ++k) cv4[k] = *(const float4*)(cp + (4*jb + k) * SP);
    #pragma unroll
    for (int q = 0; q < RT; ++q) rv4[q] = *(const float4*)(rp + q * SP + 4*jb);
    #pragma unroll
    for (int q = 0; q < RT; ++q) {
      const float rr[4] = {rv4[q].x, rv4[q].y, rv4[q].z, rv4[q].w};
      #pragma unroll
      for (int k = 0; k < 4; ++k) {
        const float cc[4] = {cv4[k].x, cv4[k].y, cv4[k].z, cv4[k].w};
        #pragma unroll
        for (int u = 0; u < CT; ++u) acc[q][u] = fmaf(rr[k], cc[u], acc[q][u]);
      }
    }
  }
  { const float4 c4 = *(const float4*)(cp + 64 * SP);
    const float cc[4] = {c4.x, c4.y, c4.z, c4.w};
    #pragma unroll
    for (int q = 0; q < RT; ++q) {
      float rr = rp[q * SP + 64];
      #pragma unroll
      for (int u = 0; u < CT; ++u) acc[q][u] = fmaf(rr, cc[u], acc[q][u]);
    } }
}

// ---------- K1a: softmax(log_trans) -> a_prob[65][SP]
__global__ void k_trans_prep(const float* __restrict__ lt, float* __restrict__ a_prob) {
  int i = blockIdx.x, t = threadIdx.x;
  float x0 = lt[i*S + t];
  float x1 = (t == 0) ? lt[i*S + 64] : -1e30f;
  float m = wave_max(fmaxf(x0, x1));
  float e0 = expf(x0 - m);
  float e1 = (t == 0) ? expf(x1 - m) : 0.f;
  float inv = 1.f / wave_sumf(e0 + e1);
  a_prob[i*SP + t] = e0 * inv;
  if (t == 0) a_prob[i*SP + 64] = e1 * inv;
  if (t < 3)  a_prob[i*SP + 65 + t] = 0.f;
}

// ---------- K1b: softmax(log_em) -> em_pT[v][j] transposed
__global__ __launch_bounds__(NTH) void k_em_prep(const float* __restrict__ le,
                                                 float* __restrict__ em_pT) {
  int j = blockIdx.x, t = threadIdx.x;
  const float* row = le + (size_t)j * VOCAB;
  float x[4]; float m = -1e30f;
  #pragma unroll
  for (int q = 0; q < 4; ++q) { x[q] = row[t + 256*q]; m = fmaxf(m, x[q]); }
  m = wave_max(m);
  __shared__ float wred[4], wsum[4];
  int w = t >> 6, lane = t & 63;
  if (lane == 0) wred[w] = m;
  __syncthreads();
  m = fmaxf(fmaxf(wred[0], wred[1]), fmaxf(wred[2], wred[3]));
  float s = 0.f;
  #pragma unroll
  for (int q = 0; q < 4; ++q) s += expf(x[q] - m);
  s = wave_sumf(s);
  if (lane == 0) wsum[w] = s;
  __syncthreads();
  float inv = 1.f / (wsum[0] + wsum[1] + wsum[2] + wsum[3]);
  #pragma unroll
  for (int q = 0; q < 4; ++q)
    em_pT[(size_t)(t + 256*q) * EMS + j] = expf(x[q] - m) * inv;
}

// ---------- K2: C_v = A*diag(e_v)*A, emitted TRANSPOSED as bf16 h/l frags + f32 borders
__global__ __launch_bounds__(NTH) void k_pair(const float* __restrict__ a_prob,
                                              const float* __restrict__ em_pT,
                                              char* __restrict__ Ctab) {
  __shared__ __align__(16) float aL[REC];
  __shared__ __align__(16) float bL[REC];
  __shared__ __align__(16) float cL[REC];
  int v = blockIdx.x, t = threadIdx.x;
  { const float4* src = (const float4*)a_prob; float4* dst = (float4*)aL;
    for (int u = t; u < F4; u += NTH) dst[u] = src[u]; }
  __syncthreads();
  for (int u = t; u < REC; u += NTH) {
    int j = u / SP;
    bL[u] = em_pT[(size_t)v * EMS + j] * aL[u];
  }
  __syncthreads();
  int rt = t / 17, ct = t % 17;
  bool act = rt < 13;
  int r0 = act ? rt * RT : 0;
  int c0 = ct * CT;
  float acc[RT][CT] = {};
  mm_tile(aL, bL, r0, c0, acc);
  if (act) {
    #pragma unroll
    for (int q = 0; q < RT; ++q) {
      float4 o; o.x = acc[q][0]; o.y = acc[q][1]; o.z = acc[q][2]; o.w = acc[q][3];
      *(float4*)(cL + (r0+q)*SP + c0) = o;
    }
  }
  __syncthreads();
  char* Cv = Ctab + (size_t)v * ATS;
  // frag chunks: c<512 -> h at c*16; c>=512 -> l at c*16 (=8192+..)
  for (int c = t; c < 1024; c += NTH) {
    int hl = c >> 9, r = c & 511;
    int mi = r >> 7, ks = (r >> 6) & 1, ln = r & 63;
    int row = 16*mi + (ln & 15);          // A row (= C col, table is transposed)
    int kb = 32*ks + 8*(ln >> 4);
    unsigned wd[4];
    #pragma unroll
    for (int eo = 0; eo < 4; ++eo) {
      float x0 = cL[(kb + 2*eo    )*SP + row];   // A[row][k] = C[k][row]
      float x1 = cL[(kb + 2*eo + 1)*SP + row];
      unsigned short b0, b1;
      if (hl == 0) { b0 = f2bf(x0); b1 = f2bf(x1); }
      else {
        unsigned short h0 = f2bf(x0), h1 = f2bf(x1);
        b0 = tbf(x0 - bf2f(h0)); b1 = tbf(x1 - bf2f(h1));
      }
      wd[eo] = (unsigned)b0 | ((unsigned)b1 << 16);
    }
    uint4 o; o.x = wd[0]; o.y = wd[1]; o.z = wd[2]; o.w = wd[3];
    *(uint4*)(Cv + c*16) = o;
  }
  if (t < 72) {
    float r64 = (t < S) ? cL[t*SP + 64] : 0.f;   // T64[k]  = C[k][64]
    float c64 = (t < S) ? cL[64*SP + t] : 0.f;   // Tc64[i] = C[64][i]
    ((float*)(Cv + A_R64))[t] = r64;
    ((float*)(Cv + A_C64))[t] = c64;
  }
}

// ---------- K3: MFMA segment chain. Table frags in REGISTERS (direct global loads);
//               state = S^T as bf16 h/l B-frags in LDS + f32 borders.
__global__ __launch_bounds__(NTH, 4) void k_seg(const char* __restrict__ Ctab,
    const float* __restrict__ em_pT, const int* __restrict__ obvs,
    float* __restrict__ Rseg, int* __restrict__ eacc_out, int NP, int nseg) {
  __shared__ __align__(16) char Sf[16384];       // h: 0..8191, l: 8192..16383
  __shared__ __align__(16) float Tb[2][144];     // staged borders: T64[72] | Tc64[72]
  __shared__ __align__(16) float evb[2][72];
  __shared__ __align__(16) float Srow64[72];
  __shared__ __align__(16) float Scol64[72];
  __shared__ float Scorner;
  __shared__ int smax[2];

  const int p = blockIdx.x, t = threadIdx.x;
  const int w = t >> 6, l = t & 63;
  const int h4 = l >> 4, l15 = l & 15;
  const int miq = (w >> 1) * 2, niq = (w & 1) * 2;
  const int base = NP / nseg, rem = NP % nseg;
  const int k0 = p*base + (p < rem ? p : rem);
  const int L  = base + (p < rem ? 1 : 0);

  for (int u = t; u < 1024; u += NTH) ((float4*)Sf)[u] = make_float4(0.f,0.f,0.f,0.f);
  if (t < 72) { Srow64[t] = 0.f; Scol64[t] = 0.f; }
  if (t == 0) { smax[0] = 0; smax[1] = 0; }
  __syncthreads();
  if (t < 64) {  // identity diagonal (h = bf16 1.0)
    int blk = (t >> 4)*2 + (t >> 5);
    int ln  = (t & 15) + 16*((t & 31) >> 3);
    *(unsigned short*)(Sf + blk*1024 + ln*16 + (t & 7)*2) = 0x3F80;
  }
  if (t == 0) Scorner = 1.f;
  {
    int o1 = obvs[1 + 2*k0], o2 = obvs[2 + 2*k0];
    if (t < 36) gld16((const float4*)(Ctab + (size_t)o1 * ATS + A_R64) + t,
                      (float4*)(Tb[0]) + t);
    if (t < 72) evb[0][t] = (t < S) ? em_pT[(size_t)o2 * EMS + t] : 0.f;
  }
  __syncthreads();

  int my_e = 0;
  float scale = 1.f;
  for (int s = 0; s < L; ++s) {
    const int sb = s & 1;
    if (s > 0) {
      int bm = smax[sb ^ 1];
      int e = (bm >> 23) - 127;
      my_e += e;
      scale = __int_as_float((127 - e) << 23);
    }
    // ---- issue table-frag loads for THIS step straight to registers
    int o1 = obvs[1 + 2*(k0 + s)];
    const char* A = Ctab + (size_t)o1 * ATS;
    bf16x8 ah0[2], ah1[2], al0[2], al1[2];
    #pragma unroll
    for (int ks = 0; ks < 2; ++ks) {
      ah0[ks] = *(const bf16x8*)(A + ((miq  )*2+ks)*1024 + l*16);
      ah1[ks] = *(const bf16x8*)(A + ((miq+1)*2+ks)*1024 + l*16);
      al0[ks] = *(const bf16x8*)(A + 8192 + ((miq  )*2+ks)*1024 + l*16);
      al1[ks] = *(const bf16x8*)(A + 8192 + ((miq+1)*2+ks)*1024 + l*16);
    }
    // ---- stage NEXT step's borders (DMA) + emission vector (regs)
    int kn = k0 + s + 1; if (kn > NP - 1) kn = NP - 1;
    int o1n = obvs[1 + 2*kn], o2n = obvs[2 + 2*kn];
    if (t < 36) gld16((const float4*)(Ctab + (size_t)o1n * ATS + A_R64) + t,
                      (float4*)(Tb[sb ^ 1]) + t);
    float evreg = (t < S) ? em_pT[(size_t)o2n * EMS + t] : 0.f;

    const float* T64  = Tb[sb];        // T64[k]  = C[k][64]
    const float* Tc64 = Tb[sb] + 72;   // Tc64[i] = C[64][i]

    // ---- border pass R FIRST (state + borders only; covers A-load latency)
    float pr = 0.f;
    #pragma unroll
    for (int ks = 0; ks < 2; ++ks) {
      uint4 hb = *(const uint4*)(Sf + (w*2+ks)*1024 + l*16);
      uint4 lb = *(const uint4*)(Sf + 8192 + (w*2+ks)*1024 + l*16);
      const float* tp = T64 + 32*ks + 8*h4;
      float4 ta = *(const float4*)tp, tb = *(const float4*)(tp + 4);
      pr += blo(hb.x,lb.x)*ta.x + bhi(hb.x,lb.x)*ta.y
          + blo(hb.y,lb.y)*ta.z + bhi(hb.y,lb.y)*ta.w
          + blo(hb.z,lb.z)*tb.x + bhi(hb.z,lb.z)*tb.y
          + blo(hb.w,lb.w)*tb.z + bhi(hb.w,lb.w)*tb.w;
    }
    pr += __shfl_xor(pr, 16); pr += __shfl_xor(pr, 32);
    pr += T64[64] * Srow64[16*w + l15];
    float ev64 = evb[sb][64];
    float nrow = ev64 * scale * pr;

    // ---- interior MFMA: P = C^T * S^T, 64x64 in 4 16x16 tiles per wave
    f32x4 acc00 = {0.f,0.f,0.f,0.f}, acc01 = acc00, acc10 = acc00, acc11 = acc00;
    #pragma unroll
    for (int ks = 0; ks < 2; ++ks) {
      bf16x8 bh0 = *(const bf16x8*)(Sf + ((niq  )*2+ks)*1024 + l*16);
      bf16x8 bh1 = *(const bf16x8*)(Sf + ((niq+1)*2+ks)*1024 + l*16);
      bf16x8 bl0 = *(const bf16x8*)(Sf + 8192 + ((niq  )*2+ks)*1024 + l*16);
      bf16x8 bl1 = *(const bf16x8*)(Sf + 8192 + ((niq+1)*2+ks)*1024 + l*16);
      acc00 = MFMA(ah0[ks], bh0, acc00); acc00 = MFMA(ah0[ks], bl0, acc00); acc00 = MFMA(al0[ks], bh0, acc00);
      acc01 = MFMA(ah0[ks], bh1, acc01); acc01 = MFMA(ah0[ks], bl1, acc01); acc01 = MFMA(al0[ks], bh1, acc01);
      acc10 = MFMA(ah1[ks], bh0, acc10); acc10 = MFMA(ah1[ks], bl0, acc10); acc10 = MFMA(al1[ks], bh0, acc10);
      acc11 = MFMA(ah1[ks], bh1, acc11); acc11 = MFMA(ah1[ks], bl1, acc11); acc11 = MFMA(al1[ks], bh1, acc11);
    }

    // ---- border pass C: wave w computes P[i][64], i = 16w+l15 (A regs reused!)
    float pc = 0.f;
    #pragma unroll
    for (int ks = 0; ks < 2; ++ks) {
      uint4 ha = asu4((w & 1) ? ah1[ks] : ah0[ks]);
      uint4 la = asu4((w & 1) ? al1[ks] : al0[ks]);
      const float* sp2 = Scol64 + 32*ks + 8*h4;
      float4 sa = *(const float4*)sp2, sb2 = *(const float4*)(sp2 + 4);
      pc += blo(ha.x,la.x)*sa.x + bhi(ha.x,la.x)*sa.y
          + blo(ha.y,la.y)*sa.z + bhi(ha.y,la.y)*sa.w
          + blo(ha.z,la.z)*sb2.x + bhi(ha.z,la.z)*sb2.y
          + blo(ha.w,la.w)*sb2.z + bhi(ha.w,la.w)*sb2.w;
    }
    pc += __shfl_xor(pc, 16); pc += __shfl_xor(pc, 32);
    pc += Tc64[16*w + l15] * Scorner;
    float ncol = evb[sb][16*w + l15] * scale * pc;

    // ---- corner P[64][64] (wave 3)
    float ncorner = 0.f;
    if (w == 3) {
      float pq = T64[l] * Scol64[l];
      pq = wave_sumf(pq);
      pq += T64[64] * Scorner;
      ncorner = ev64 * scale * pq;
    }

    // ---- rank-1 (k=64) into interior: acc += Tc64[i] * Srow64[j]
    {
      float4 tc0 = *(const float4*)(Tc64 + 16*miq + 4*h4);
      float4 tc1 = *(const float4*)(Tc64 + 16*(miq+1) + 4*h4);
      float r0j = Srow64[16*niq + l15], r1j = Srow64[16*(niq+1) + l15];
      acc00.x += tc0.x*r0j; acc00.y += tc0.y*r0j; acc00.z += tc0.z*r0j; acc00.w += tc0.w*r0j;
      acc01.x += tc0.x*r1j; acc01.y += tc0.y*r1j; acc01.z += tc0.z*r1j; acc01.w += tc0.w*r1j;
      acc10.x += tc1.x*r0j; acc10.y += tc1.y*r0j; acc10.z += tc1.z*r0j; acc10.w += tc1.w*r0j;
      acc11.x += tc1.x*r1j; acc11.y += tc1.y*r1j; acc11.z += tc1.z*r1j; acc11.w += tc1.w*r1j;
    }
    // ---- interior block max (pre-emission)
    float mx = fmaxf(fmaxf(fmaxf(acc00.x,acc00.y),fmaxf(acc00.z,acc00.w)),
               fmaxf(fmaxf(acc01.x,acc01.y),fmaxf(acc01.z,acc01.w)));
    mx = fmaxf(mx, fmaxf(fmaxf(fmaxf(acc10.x,acc10.y),fmaxf(acc10.z,acc10.w)),
                   fmaxf(fmaxf(acc11.x,acc11.y),fmaxf(acc11.z,acc11.w))));
    mx = wave_max(mx);
    if (l == 0) atomicMax(&smax[sb], __float_as_int(mx));

    __syncthreads();   // barrier A: all reads of state done; staging DMA drained

    if (t < 72) evb[sb ^ 1][t] = evreg;
    if (t == 0) smax[sb ^ 1] = 0;
    if (l < 16) { Srow64[16*w + l15] = nrow; Scol64[16*w + l15] = ncol; }
    if (w == 3 && l == 0) Scorner = ncorner;
    {
      float4 ev0 = *(const float4*)(&evb[sb][16*miq + 4*h4]);
      float4 ev1 = *(const float4*)(&evb[sb][16*(miq+1) + 4*h4]);
      float e0x = ev0.x*scale, e0y = ev0.y*scale, e0z = ev0.z*scale, e0w = ev0.w*scale;
      float e1x = ev1.x*scale, e1y = ev1.y*scale, e1z = ev1.z*scale, e1w = ev1.w*scale;
      auto wb = [&](const f32x4& a, float sx, float sy, float sz, float sw, int mi, int ni) {
        float v0 = a.x*sx, v1 = a.y*sy, v2 = a.z*sz, v3 = a.w*sw;
        unsigned short h0=f2bf(v0), h1=f2bf(v1), h2=f2bf(v2), h3=f2bf(v3);
        unsigned hw0 = (unsigned)h0 | ((unsigned)h1<<16);
        unsigned hw1 = (unsigned)h2 | ((unsigned)h3<<16);
        unsigned short q0=tbf(v0-bf2f(h0)), q1=tbf(v1-bf2f(h1)),
                       q2=tbf(v2-bf2f(h2)), q3=tbf(v3-bf2f(h3));
        unsigned lw0 = (unsigned)q0 | ((unsigned)q1<<16);
        unsigned lw1 = (unsigned)q2 | ((unsigned)q3<<16);
        char* dst = Sf + (ni*2 + (mi>>1))*1024
                       + (l15 + 16*(2*(mi&1) + (h4>>1)))*16 + (h4&1)*8;
        *(uint2*)dst          = make_uint2(hw0, hw1);
        *(uint2*)(dst + 8192) = make_uint2(lw0, lw1);
      };
      wb(acc00, e0x,e0y,e0z,e0w, miq,   niq  );
      wb(acc01, e0x,e0y,e0z,e0w, miq,   niq+1);
      wb(acc10, e1x,e1y,e1z,e1w, miq+1, niq  );
      wb(acc11, e1x,e1y,e1z,e1w, miq+1, niq+1);
    }
    __syncthreads();   // barrier B: new state visible
  }

  // emit segment matrix (S^T) as compact fp32 [65][SP], zero pads
  for (int u = t; u < REC; u += NTH) {
    int k = u / SP, j = u - k*SP;
    float f = 0.f;
    if (j < S) {
      if (k == 64)      f = (j == 64) ? Scorner : Srow64[j];
      else if (j == 64) f = Scol64[k];
      else {
        int blk = (j >> 4)*2 + (k >> 5);
        int ln  = (j & 15) + 16*((k & 31) >> 3);
        const char* bp = Sf + blk*1024 + ln*16 + (k & 7)*2;
        unsigned hh = *(const unsigned short*)bp;
        unsigned ll = *(const unsigned short*)(bp + 8192);
        f = __uint_as_float(hh << 16) + __uint_as_float(ll << 16);
      }
    }
    Rseg[(size_t)p*REC + u] = f;
  }
  if (t == 0) eacc_out[p] = my_e;
}

// ---------- K4: chain `group` consecutive transposed matrices: T <- G_q * T
__global__ __launch_bounds__(NTH) void k_chain(const float* __restrict__ src,
    float* __restrict__ dst, int* __restrict__ eacc, int group) {
  __shared__ __align__(16) float Rb[2][REC];
  __shared__ __align__(16) float Cb[REC];
  __shared__ int smax[2];
  const int g = blockIdx.x, t = threadIdx.x;
  const int rt = t / 17, ct = t % 17;
  const bool act = rt < 13;
  const int r0 = act ? rt * RT : 0;
  const int c0 = ct * CT;
  { const float4* s4 = (const float4*)(src + (size_t)(g*group) * REC);
    float4* d4 = (float4*)(Rb[0]);
    for (int u = t; u < F4; u += NTH) d4[u] = s4[u]; }
  if (t == 0) { smax[0] = 0; smax[1] = 0; }
  __syncthreads();
  int cur = 0, my_e = 0;
  for (int q2 = 1; q2 < group; ++q2) {
    { const float4* s4 = (const float4*)(src + (size_t)(g*group + q2) * REC);
      float4* d4 = (float4*)Cb;
      for (int u = t; u < F4; u += NTH) d4[u] = s4[u]; }
    __syncthreads();
    float acc[RT][CT] = {};
    mm_tile(Cb, Rb[cur], r0, c0, acc);      // left-multiply: new = G_q * T
    float mx = 0.f;
    if (act) {
      #pragma unroll
      for (int q = 0; q < RT; ++q)
        #pragma unroll
        for (int u = 0; u < CT; ++u) mx = fmaxf(mx, acc[q][u]);
    }
    mx = wave_max(mx);
    if ((t & 63) == 0) atomicMax(&smax[q2 & 1], __float_as_int(mx));
    __syncthreads();
    int bm = smax[q2 & 1];
    int e = (bm >> 23) - 127;
    float scale = __int_as_float((127 - e) << 23);
    my_e += e;
    if (t == 0) smax[(q2+1) & 1] = 0;
    if (act) {
      float* rdst = Rb[cur ^ 1] + r0*SP + c0;
      #pragma unroll
      for (int q = 0; q < RT; ++q) {
        float4 o;
        o.x = acc[q][0]*scale; o.y = acc[q][1]*scale;
        o.z = acc[q][2]*scale; o.w = acc[q][3]*scale;
        *(float4*)(rdst + q*SP) = o;
      }
    }
    __syncthreads();
    cur ^= 1;
  }
  { const float4* s4 = (const float4*)(Rb[cur]);
    float4* d4 = (float4*)(dst + (size_t)g * REC);
    for (int u = t; u < F4; u += NTH) d4[u] = s4[u]; }
  if (t == 0) eacc[g] = my_e;
}

// ---------- K5: final sweep (group matrices are transposed: row-t dot)
__global__ __launch_bounds__(NTH) void k_final(const float* __restrict__ Rm,
    const float* __restrict__ lt, const int* __restrict__ e1,
    const int* __restrict__ e2, const int* __restrict__ e3,
    const float* __restrict__ a_prob, const float* __restrict__ em_pT,
    const int* __restrict__ obvs, float* __restrict__ out, int N,
    int nseg, int ng1, int ng2) {
  __shared__ __align__(16) float Mb[2][REC];
  __shared__ float vL[SP];
  __shared__ float prod[SP];
  __shared__ int smax[2];
  __shared__ int esum_s;
  const int t = threadIdx.x, lane = t & 63;
  if (t == 0) { esum_s = 0; smax[0] = 0; smax[1] = 0; }
  if (t < S) vL[t] = (t == 0) ? 1.f : expf(-20.0f);
  { const float4* src = (const float4*)Rm;
    float4* dst = (float4*)(Mb[0]);
    for (int u = t; u < F4; u += NTH) dst[u] = src[u]; }
  __syncthreads();
  {
    int es = 0;
    for (int u = t; u < nseg; u += NTH) es += e1[u];
    for (int u = t; u < ng1; u += NTH) es += e2[u];
    for (int u = t; u < ng2; u += NTH) es += e3[u];
    es = wave_sumi(es);
    if (lane == 0) atomicAdd(&esum_s, es);
  }
  int cur = 0, my_e = 0;
  for (int m = 0; m < ng2; ++m) {
    if (m + 1 < ng2) {
      const float4* src = (const float4*)(Rm + (size_t)(m+1) * REC);
      float4* dst = (float4*)(Mb[cur ^ 1]);
      for (int u = t; u < F4; u += NTH) dst[u] = src[u];
    }
    float acc = 0.f;
    if (t < S) {
      const float* Mp = Mb[cur];
      #pragma unroll 5
      for (int i = 0; i < S; ++i) acc = fmaf(vL[i], Mp[t*SP + i], acc);  // row-t (transposed)
    }
    float mx = (t < S) ? acc : 0.f;
    mx = wave_max(mx);
    if (lane == 0) atomicMax(&smax[m & 1], __float_as_int(mx));
    __syncthreads();
    int bm = smax[m & 1];
    int e = (bm >> 23) - 127;
    float scale = __int_as_float((127 - e) << 23);
    my_e += e;
    if (t == 0) smax[(m+1) & 1] = 0;
    if (t < S) vL[t] = acc * scale;
    __syncthreads();
    cur ^= 1;
  }
  if (N & 1) {
    int oN = obvs[N];
    float acc2 = 0.f;
    if (t < S) {
      #pragma unroll 5
      for (int i = 0; i < S; ++i) acc2 = fmaf(vL[i], a_prob[i*SP + t], acc2);
      acc2 *= em_pT[(size_t)oN * EMS + t];
    }
    __syncthreads();
    if (t < S) vL[t] = acc2;
    __syncthreads();
  }
  if (t < S) prod[t] = vL[t] * expf(lt[t*S]);
  __syncthreads();
  if (t == 0) {
    double z = 0.0;
    for (int i = 0; i < S; ++i) z += (double)prod[i];
    double logz = log(z) + (double)(esum_s + my_e) * 0.69314718055994530942;
    out[0] = (float)logz;
  }
}

extern "C" void kernel_launch(void* const* d_in, const int* in_sizes, int n_in,
                              void* d_out, int out_size, void* d_ws, size_t ws_size,
                              hipStream_t stream) {
  (void)n_in; (void)out_size;
  const int*   obvs = (const int*)d_in[0];
  const float* lt   = (const float*)d_in[1];
  const float* le   = (const float*)d_in[2];
  float* out = (float*)d_out;
  const int T  = in_sizes[0];
  const int N  = T - 2;
  const int NP = N >> 1;

  // fixed-layout prefix: a_prob | em_pT | Ctab | e1(1024) | e2(128) | e3(16)
  float* ws = (float*)d_ws;
  size_t off = 0;
  float* a_prob = ws + off; off += REC;                       // 4,420
  float* em_pT  = ws + off; off += (size_t)VOCAB * EMS;       // 69,632
  char*  Ctab   = (char*)(ws + off); off += (size_t)VOCAB * (ATS/4);  // 4,341,760
  int* e1 = (int*)(ws + off); off += 1024;
  int* e2 = (int*)(ws + off); off += 128;
  int* e3 = (int*)(ws + off); off += 16;
  float* Rseg   = ws + off;                                   // variable size

  // Rm1/Rm2 alias the Ctab region (dead after k_seg completes; stream-ordered)
  float* Rm1 = (float*)Ctab;
  // config: primary 1024/8/8 if workspace allows, else proven-fit 768/12/8
  const size_t need1024 = (off + (size_t)1024 * REC) * sizeof(float);
  int nseg, g1, g2;
  if (ws_size >= need1024) { nseg = 1024; g1 = 8;  g2 = 8; }
  else                     { nseg = 768;  g1 = 12; g2 = 8; }
  const int ng1 = nseg / g1;            // 128 or 64
  const int ng2 = ng1 / g2;             // 16 or 8
  float* Rm2 = Rm1 + (size_t)ng1 * REC;
  if (ws_size < (off + (size_t)nseg * REC) * sizeof(float)) return;

  k_trans_prep<<<dim3(S), dim3(64), 0, stream>>>(lt, a_prob);
  k_em_prep  <<<dim3(S), dim3(NTH), 0, stream>>>(le, em_pT);
  k_pair     <<<dim3(VOCAB), dim3(NTH), 0, stream>>>(a_prob, em_pT, Ctab);
  k_seg      <<<dim3(nseg), dim3(NTH), 0, stream>>>(Ctab, em_pT, obvs, Rseg, e1, NP, nseg);
  k_chain    <<<dim3(ng1), dim3(NTH), 0, stream>>>(Rseg, Rm1, e2, g1);
  k_chain    <<<dim3(ng2), dim3(NTH), 0, stream>>>(Rm1, Rm2, e3, g2);
  k_final    <<<dim3(1), dim3(NTH), 0, stream>>>(Rm2, lt, e1, e2, e3,
                                                 a_prob, em_pT, obvs, out, N,
                                                 nseg, ng1, ng2);
}